// Round 9
// baseline (100.894 us; speedup 1.0000x reference)
//
#include <hip/hip_runtime.h>
#include <math.h>

// ret[t] = r[t] + g*ret[t+1]; out = (ret-mean)/(std+eps).
// R9: contiguous-lane ownership to kill cross-lane DS cost.
// Evidence R1-R8: all scan variants cluster ~100us with ~70-85 DS instrs per
// 2048 elems (dependent ds_bpermute chains, latency-exposed at 1-2 waves/SIMD);
// k_norm (0 DS ops) streams 256MB in ~10us. This version: lane owns 32
// CONTIGUOUS elems -> serial Horner (VALU, 0 shuffles); ONE 6-level butterfly
// over lane aggregates (mult gamma^(32d)) + shift + bcast = 8 shuffles/chunk.
// LDS swizzle (both-sides involution, pre-swizzled global src for
// global_load_lds) keeps ds_read_b128 at the bank floor. Outputs round-trip
// through the consumed buffer -> coalesced global stores.
// Pipeline: double-buffer, depth-1 prefetch, counted vmcnt(16) (R8-proven).

#define GAMMA 0.99f
#define EPSN  1e-4

constexpr int WCH   = 2048;          // elems per chunk = 512 slots of 16B
constexpr int CPW   = 8;             // chunks per wave
constexpr int SUPER = WCH * CPW;     // 16384 contiguous elems per wave
constexpr int LAW   = 1024;          // lookahead elems (gamma^1024 ~ 3e-5)
constexpr int NACC  = 32;            // atomic slot pairs

__host__ __device__ constexpr float gpow(int k) {
  double p = 1.0;
  for (int i = 0; i < k; ++i) p *= 0.99;
  return (float)p;
}
constexpr float LOG2G = -0.014499569695f;   // log2(0.99)

__device__ __forceinline__ float4 load4g(const float* __restrict__ p, long long i, long long n) {
  if (i + 3 < n) return *reinterpret_cast<const float4*>(p + i);
  float4 v = make_float4(0.f, 0.f, 0.f, 0.f);
  if (i < n)     v.x = p[i];
  if (i + 1 < n) v.y = p[i + 1];
  if (i + 2 < n) v.z = p[i + 2];
  return v;
}

__device__ __forceinline__ void store4g(float* __restrict__ p, long long i, long long n, float4 v) {
  if (i + 3 < n) { *reinterpret_cast<float4*>(p + i) = v; return; }
  if (i < n)     p[i] = v.x;
  if (i + 1 < n) p[i + 1] = v.y;
  if (i + 2 < n) p[i + 2] = v.z;
}

__device__ __forceinline__ void gll16(const float* g, float* l) {
  __builtin_amdgcn_global_load_lds(
      (const __attribute__((address_space(1))) void*)g,
      (__attribute__((address_space(3))) void*)l, 16, 0, 0);
}

#define WAITVM(N)                                               \
  do {                                                          \
    asm volatile("s_waitcnt vmcnt(" #N ")" ::: "memory");       \
    __builtin_amdgcn_sched_barrier(0);                          \
  } while (0)

// stage one chunk; global source pre-permuted by the involution sigma so that
// LDS slot u holds G slot sigma(u). 8 coalesced 1KB loads.
__device__ __forceinline__ void stage_chunk(const float* __restrict__ r, long long gbase,
                                            float* buf, int kperm4) {
  __builtin_amdgcn_sched_barrier(0);
#pragma unroll
  for (int j = 0; j < 8; ++j)
    gll16(r + gbase + 256 * j + kperm4, buf + 256 * j);
  __builtin_amdgcn_sched_barrier(0);
}

// lookahead reduction (quad layout): ret value at la0 assuming 0 beyond +LAW
__device__ __forceinline__ float la_reduce(const float4 (&lq)[4], float w4) {
  float t[4];
#pragma unroll
  for (int k = 0; k < 4; ++k) {
    const float h = fmaf(GAMMA, fmaf(GAMMA, fmaf(GAMMA, lq[k].w, lq[k].z), lq[k].y), lq[k].x);
    t[k] = h * w4;
  }
#pragma unroll
  for (int i = 0; i < 6; ++i) {
    const int d = 1 << i;
#pragma unroll
    for (int k = 0; k < 4; ++k) t[k] += __shfl_xor(t[k], d);
  }
  constexpr float G256 = gpow(256);
  return fmaf(G256, fmaf(G256, fmaf(G256, t[3], t[2]), t[1]), t[0]);
}

// process one chunk from swizzled LDS buf. Lane owns elems [32*lane, +32).
// C = exact ret at chunk end. Returns ret[chunk_start]. 8 shuffles total.
__device__ __forceinline__ float proc(float* buf, float C, int lane, const float* mul,
                                      float wM, int kperm4, float* __restrict__ out,
                                      long long gbase, float& sm, float& sq) {
  const int l7 = lane & 7;
  float4 q[8];
#pragma unroll
  for (int j = 0; j < 8; ++j)
    q[j] = *reinterpret_cast<const float4*>(buf + 32 * lane + 4 * (j ^ l7));

  // lane aggregate: agg = sum_{i<32} gamma^i * r_i  (pure VALU, descending)
  float h = 0.f;
#pragma unroll
  for (int j = 7; j >= 0; --j) {
    h = fmaf(GAMMA, h, q[j].w); h = fmaf(GAMMA, h, q[j].z);
    h = fmaf(GAMMA, h, q[j].y); h = fmaf(GAMMA, h, q[j].x);
  }

  // 6-level inclusive suffix butterfly over lane aggregates, mult gamma^(32d)
  float B = h;
#pragma unroll
  for (int i = 0; i < 6; ++i) {
    const float u = __shfl_down(B, 1 << i);
    B = fmaf(mul[i], u, B);                 // mul=0 guards lane+d>=64
  }
  const float Sn = __shfl_down(B, 1);       // suffix of lanes > l
  const float X  = fmaf(wM, C, (lane < 63) ? Sn : 0.f);  // carry into lane end

  // backward recurrence over own 32 elems; overwrite q with outputs; stats
  float x = X;
#pragma unroll
  for (int j = 7; j >= 0; --j) {
    x = fmaf(GAMMA, x, q[j].w); q[j].w = x; sm += x; sq = fmaf(x, x, sq);
    x = fmaf(GAMMA, x, q[j].z); q[j].z = x; sm += x; sq = fmaf(x, x, sq);
    x = fmaf(GAMMA, x, q[j].y); q[j].y = x; sm += x; sq = fmaf(x, x, sq);
    x = fmaf(GAMMA, x, q[j].x); q[j].x = x; sm += x; sq = fmaf(x, x, sq);
  }
  const float Cn = __shfl(x, 0);            // lane0's x = ret[chunk_start]

  // out round-trip: swizzled ds_write (own slots), linear ds_read, coalesced
  // permuted global store (same involution as staging). Buf already consumed.
#pragma unroll
  for (int j = 0; j < 8; ++j)
    *reinterpret_cast<float4*>(buf + 32 * lane + 4 * (j ^ l7)) = q[j];
#pragma unroll
  for (int j = 0; j < 8; ++j) {
    const float4 v = *reinterpret_cast<const float4*>(buf + 256 * j + 4 * lane);
    *reinterpret_cast<float4*>(out + gbase + 256 * j + kperm4) = v;
  }
  return Cn;
}

__global__ __launch_bounds__(64, 2)
void scan_stats(const float* __restrict__ r, long long n,
                double* __restrict__ acc, float* __restrict__ out) {
  __shared__ __align__(16) float bufA[WCH];
  __shared__ __align__(16) float bufB[WCH];

  const int lane = threadIdx.x;               // one wave per block
  const long long S = (long long)blockIdx.x * SUPER;
  if (S >= n) return;

  const int l7 = lane & 7;
  const int kperm4 = 4 * ((lane & 56) | (l7 ^ ((lane >> 3) & 7)));  // 4*sigma-slot
  const float w4 = exp2f((float)(4 * lane) * LOG2G);
  const float wM = exp2f((float)(32 * (63 - lane)) * LOG2G);        // gamma^(32(63-l))
  float mul[6];
#pragma unroll
  for (int i = 0; i < 6; ++i) {
    const int d = 1 << i;
    mul[i] = (lane + d < 64) ? gpow(32 << i) : 0.f;
  }

  float sm = 0.f, sq = 0.f;
  float C;

  if (S + SUPER <= n) {
    stage_chunk(r, S + 7LL * WCH, bufA, kperm4);
    // lookahead -> registers (once per wave)
    if (S + SUPER + LAW <= n) {
      float4 lq[4];
#pragma unroll
      for (int k = 0; k < 4; ++k)
        lq[k] = *reinterpret_cast<const float4*>(r + S + SUPER + 256 * k + 4 * lane);
      C = la_reduce(lq, w4);
    } else if (S + SUPER >= n) {
      C = 0.f;                                 // true end of array: exact
    } else {
      float4 lq[4];
#pragma unroll
      for (int k = 0; k < 4; ++k) lq[k] = load4g(r, S + SUPER + 256 * k + 4 * lane, n);
      C = la_reduce(lq, w4);
    }

    stage_chunk(r, S + 6LL * WCH, bufB, kperm4);
    WAITVM(8);                                 // retire chunk-7 loads
    C = proc(bufA, C, lane, mul, wM, kperm4, out, S + 7LL * WCH, sm, sq);

    float* cur = bufB;
    float* nxt = bufA;
#pragma unroll
    for (int c = 6; c >= 1; --c) {
      stage_chunk(r, S + (long long)(c - 1) * WCH, nxt, kperm4);
      WAITVM(16);      // retire chunk-c loads; keep 8 loads + 8 stores flying
      C = proc(cur, C, lane, mul, wM, kperm4, out, S + (long long)c * WCH, sm, sq);
      float* t = cur; cur = nxt; nxt = t;
    }
    WAITVM(8);                                 // retire chunk-0 loads
    C = proc(cur, C, lane, mul, wM, kperm4, out, S, sm, sq);
  } else {
    // ---- guarded tail superchunk (not taken for T=2^25): register path ----
    float w4tail = exp2f((float)(4 * (63 - lane)) * LOG2G);
    float gm4[6];
#pragma unroll
    for (int i = 0; i < 6; ++i) {
      const int d = 1 << i;
      gm4[i] = (lane + d < 64) ? gpow(4 << i) : 0.f;
    }
    float4 lq[4];
#pragma unroll
    for (int k = 0; k < 4; ++k) lq[k] = load4g(r, S + SUPER + 256 * k + 4 * lane, n);
    C = la_reduce(lq, w4);
    constexpr float G256 = gpow(256);
    constexpr float G1 = gpow(1), G2 = gpow(2), G3 = gpow(3), G4 = gpow(4);
    for (int c = CPW - 1; c >= 0; --c) {
      const long long base = S + (long long)c * WCH;
      if (base >= n) continue;
      float4 q[8];
#pragma unroll
      for (int j = 0; j < 8; ++j) q[j] = load4g(r, base + 256 * j + 4 * lane, n);
      float B[8];
#pragma unroll
      for (int j = 0; j < 8; ++j) {
        q[j].z = fmaf(GAMMA, q[j].w, q[j].z);
        q[j].y = fmaf(GAMMA, q[j].z, q[j].y);
        q[j].x = fmaf(GAMMA, q[j].y, q[j].x);
        B[j] = q[j].x;
      }
#pragma unroll
      for (int i = 0; i < 6; ++i) {
        const int d = 1 << i;
#pragma unroll
        for (int j = 0; j < 8; ++j) {
          const float u = __shfl_down(B[j], d);
          B[j] = fmaf(gm4[i], u, B[j]);
        }
      }
      float rt[8];
#pragma unroll
      for (int j = 0; j < 8; ++j) rt[j] = __shfl(B[j], 0);
      float V[8];
      V[7] = C;
#pragma unroll
      for (int j = 6; j >= 0; --j) V[j] = fmaf(G256, V[j + 1], rt[j + 1]);
      float o00 = 0.f;
#pragma unroll
      for (int j = 0; j < 8; ++j) {
        const float Sn = __shfl_down(B[j], 1);
        const float X  = fmaf(w4tail, V[j], (lane < 63) ? Sn : 0.f);
        const float o0 = fmaf(G4, X, q[j].x);
        const float o1 = fmaf(G3, X, q[j].y);
        const float o2 = fmaf(G2, X, q[j].z);
        const float o3 = fmaf(G1, X, q[j].w);
        sm += (o0 + o1) + (o2 + o3);
        sq = fmaf(o0, o0, sq); sq = fmaf(o1, o1, sq);
        sq = fmaf(o2, o2, sq); sq = fmaf(o3, o3, sq);
        store4g(out, base + 256 * j + 4 * lane, n, make_float4(o0, o1, o2, o3));
        if (j == 0) o00 = o0;
      }
      C = __shfl(o00, 0);
    }
  }

  // wave stats reduce -> spread double atomics
#pragma unroll
  for (int i = 0; i < 6; ++i) {
    const int d = 1 << i;
    sm += __shfl_down(sm, d);
    sq += __shfl_down(sq, d);
  }
  if (lane == 0) {
    const int slot = (int)(blockIdx.x & (NACC - 1)) * 2;
    atomicAdd(&acc[slot], (double)sm);
    atomicAdd(&acc[slot + 1], (double)sq);
  }
}

// pure streaming normalize, in-place on out (L3-dirty data)
__global__ void k_norm(float* __restrict__ out, long long n, const float* __restrict__ mi) {
  const float m = mi[0], inv = mi[1];
  const long long n4 = n >> 2;
  float4* p = reinterpret_cast<float4*>(out);
  long long i = (long long)blockIdx.x * blockDim.x + threadIdx.x;
  const long long stride = (long long)gridDim.x * blockDim.x;
  for (; i < n4; i += stride) {
    float4 v = p[i];
    v.x = (v.x - m) * inv; v.y = (v.y - m) * inv;
    v.z = (v.z - m) * inv; v.w = (v.w - m) * inv;
    p[i] = v;
  }
  if (blockIdx.x == 0 && threadIdx.x == 0) {   // scalar tail (n % 4)
    for (long long tt = n4 << 2; tt < n; ++tt) out[tt] = (out[tt] - m) * inv;
  }
}

__global__ void k_zero(double* __restrict__ acc) {
  const int t = threadIdx.x;
  if (t < 2 * NACC) acc[t] = 0.0;
}

__global__ void k_finalize(const double* __restrict__ acc, long long n, float* __restrict__ mi) {
  double S = 0.0, Q = 0.0;
  for (int i = 0; i < NACC; ++i) { S += acc[2 * i]; Q += acc[2 * i + 1]; }
  double mean = S / (double)n;
  double var  = Q / (double)n - mean * mean;
  if (var < 0.0) var = 0.0;
  mi[0] = (float)mean;
  mi[1] = (float)(1.0 / (sqrt(var) + EPSN));
}

extern "C" void kernel_launch(void* const* d_in, const int* in_sizes, int n_in,
                              void* d_out, int out_size, void* d_ws, size_t ws_size,
                              hipStream_t stream) {
  const float* r = (const float*)d_in[0];
  float* out = (float*)d_out;
  const long long n = (long long)in_sizes[0];

  double* acc = (double*)d_ws;                   // 64 doubles = 512 B
  float*  mi  = (float*)((char*)d_ws + 512);     // mean, inv_std

  const long long nsuper = (n + SUPER - 1) / SUPER;   // 2048 for T=2^25

  k_zero<<<1, 64, 0, stream>>>(acc);
  scan_stats<<<(int)nsuper, 64, 0, stream>>>(r, n, acc, out);
  k_finalize<<<1, 1, 0, stream>>>(acc, n, mi);
  k_norm<<<2048, 256, 0, stream>>>(out, n, mi);
}